// Round 2
// baseline (1854.313 us; speedup 1.0000x reference)
//
#include <hip/hip_runtime.h>
#include <hip/hip_bf16.h>
#include <stdint.h>

typedef _Float16 f16;
typedef _Float16 f16x2 __attribute__((ext_vector_type(2)));
typedef _Float16 f16x8 __attribute__((ext_vector_type(8)));
typedef float f32x4 __attribute__((ext_vector_type(4)));

#define T_STEPS 512
#define BATCH   128
#define DD      512
#define M_TOT   (T_STEPS * BATCH)   // 65536

// workspace layout (bytes)
#define XP_OFF  0                         // f16 Xproj [65536][512]   = 67,108,864 B
#define WF_OFF  (67108864)                // f16 W_in  [512][512]     =    524,288 B
#define WHP_OFF (67108864 + 524288)       // u32 Whp   [256][512]     =    524,288 B
#define WST_OFF (67108864 + 1048576)      // u32 Wst   [20][512][4]   =    163,840 B
// total ~68.3 MB

#define NV 176   // dwords (f16x2) of W_h per lane kept in VGPRs: k in [0,352)
#define NS 20    // streamed groups of 4 dwords: k in [352,512)

__device__ __forceinline__ float dot2(uint32_t w, uint32_t h, float acc) {
    return __builtin_amdgcn_fdot2(__builtin_bit_cast(f16x2, w),
                                  __builtin_bit_cast(f16x2, h), acc, false);
}

__device__ __forceinline__ f16x2 pk(float a, float b) {
    return __builtin_bit_cast(f16x2, __builtin_amdgcn_cvt_pkrtz(a, b));
}

// ---------------------------------------------------------------- prep weights
__global__ __launch_bounds__(256) void prep_kernel(
        const float* __restrict__ Win, const float* __restrict__ Wh,
        f16* __restrict__ Wf, uint32_t* __restrict__ Whp, uint32_t* __restrict__ Wst) {
    int idx = blockIdx.x * 256 + threadIdx.x;
    if (idx < 262144) Wf[idx] = (f16)Win[idx];
    if (idx < 131072) {           // Whp[kk][o] = pack(Wh[o][2kk], Wh[o][2kk+1])
        int kk = idx >> 9, o = idx & 511;
        f16x2 p; p[0] = (f16)Wh[o * 512 + 2 * kk]; p[1] = (f16)Wh[o * 512 + 2 * kk + 1];
        Whp[idx] = __builtin_bit_cast(uint32_t, p);
    }
    if (idx < 40960) {            // Wst[g][o][c], kk = 176 + 4g + c
        int g = idx >> 11, o = (idx >> 2) & 511, c = idx & 3;
        int kk = 176 + 4 * g + c;
        f16x2 p; p[0] = (f16)Wh[o * 512 + 2 * kk]; p[1] = (f16)Wh[o * 512 + 2 * kk + 1];
        Wst[idx] = __builtin_bit_cast(uint32_t, p);
    }
}

// ------------------------------------------------- Xproj = X @ Win^T + b_h (f16 out)
// direct-from-global MFMA, block=256 (2x2 waves), tile 128x128, grid (4, 512)
__global__ __launch_bounds__(256) void gemm_kernel(
        const float* __restrict__ X, const f16* __restrict__ Wf,
        const float* __restrict__ bias, f16* __restrict__ Xp) {
    const int lane = threadIdx.x & 63, wave = threadIdx.x >> 6;
    const int wm = wave >> 1, wn = wave & 1;
    const int q = lane >> 4, rl = lane & 15;
    const int m0 = blockIdx.y * 128 + wm * 64;
    const int n0 = blockIdx.x * 128 + wn * 64;

    f32x4 acc[4][4] = {};
    for (int k0 = 0; k0 < 512; k0 += 32) {
        const int k = k0 + q * 8;
        f16x8 af[4], bf[4];
#pragma unroll
        for (int i = 0; i < 4; i++) {
            const float* ap = X + (size_t)(m0 + i * 16 + rl) * 512 + k;
            float4 a0 = *(const float4*)ap;
            float4 a1 = *(const float4*)(ap + 4);
            f16x2 p0 = pk(a0.x, a0.y);
            f16x2 p1 = pk(a0.z, a0.w);
            f16x2 p2 = pk(a1.x, a1.y);
            f16x2 p3 = pk(a1.z, a1.w);
            f16x8 t;
            t[0] = p0[0]; t[1] = p0[1]; t[2] = p1[0]; t[3] = p1[1];
            t[4] = p2[0]; t[5] = p2[1]; t[6] = p3[0]; t[7] = p3[1];
            af[i] = t;
            bf[i] = *(const f16x8*)(Wf + (size_t)(n0 + i * 16 + rl) * 512 + k);
        }
#pragma unroll
        for (int i = 0; i < 4; i++)
#pragma unroll
            for (int j = 0; j < 4; j++)
                acc[i][j] = __builtin_amdgcn_mfma_f32_16x16x32_f16(af[i], bf[j], acc[i][j], 0, 0, 0);
    }
    // epilogue: C[row = q*4+r (+16i +64wm +128bm)][col = rl (+16j +64wn +128bn)]
#pragma unroll
    for (int j = 0; j < 4; j++) {
        const int n = n0 + j * 16 + rl;
        const float bn = bias[n];
#pragma unroll
        for (int i = 0; i < 4; i++) {
#pragma unroll
            for (int r = 0; r < 4; r++) {
                const int m = m0 + i * 16 + q * 4 + r;
                Xp[(size_t)m * 512 + n] = (f16)(acc[i][j][r] + bn);
            }
        }
    }
}

// ----------------------------------------------------------------- recurrence
// 128 WGs (one per batch), 512 threads (lane = output o). W_h: 176 dwords in
// VGPRs + 20x dwordx4 streamed from L2 per step. h broadcast via LDS uint4,
// triple-buffered -> one barrier per step.
__global__ __launch_bounds__(512) void rnn_kernel(
        const uint32_t* __restrict__ Whp, const uint32_t* __restrict__ Wst,
        const f16* __restrict__ Xp, float* __restrict__ out) {
    const int b = blockIdx.x;
    const int tid = threadIdx.x;

    __shared__ __align__(16) uint32_t hbuf[3][256];

    uint32_t wv[NV];
#pragma unroll
    for (int j = 0; j < NV; j++) wv[j] = Whp[j * 512 + tid];

    if (tid < 256) hbuf[0][tid] = 0u;   // h_0 = 0
    __syncthreads();

    const f16* xp_ptr = Xp + (size_t)b * 512 + tid;
    float h_new = 0.f;
    int rb = 0;
    for (int t = 0; t < T_STEPS; t++) {
        float acc = (float)xp_ptr[(size_t)t * (BATCH * 512)];
        const uint4* hb4 = (const uint4*)hbuf[rb];
#pragma unroll
        for (int c = 0; c < NV / 4; c++) {        // k in [0,352): VGPR weights
            uint4 hv = hb4[c];
            acc = dot2(wv[4 * c + 0], hv.x, acc);
            acc = dot2(wv[4 * c + 1], hv.y, acc);
            acc = dot2(wv[4 * c + 2], hv.z, acc);
            acc = dot2(wv[4 * c + 3], hv.w, acc);
        }
#pragma unroll
        for (int g = 0; g < NS; g++) {            // k in [352,512): L2 stream
            uint4 wq = *(const uint4*)(Wst + ((size_t)g * 512 + tid) * 4);
            uint4 hv = hb4[NV / 4 + g];
            acc = dot2(wq.x, hv.x, acc);
            acc = dot2(wq.y, hv.y, acc);
            acc = dot2(wq.z, hv.z, acc);
            acc = dot2(wq.w, hv.w, acc);
        }
        h_new = 1.0f / (1.0f + __expf(-acc));
        const int wb = (rb == 2) ? 0 : rb + 1;
        ((f16*)hbuf[wb])[tid] = (f16)h_new;       // ds_write_b16
        __syncthreads();
        rb = wb;
    }
    out[(size_t)b * 512 + tid] = h_new;
}

extern "C" void kernel_launch(void* const* d_in, const int* in_sizes, int n_in,
                              void* d_out, int out_size, void* d_ws, size_t ws_size,
                              hipStream_t stream) {
    const float* X   = (const float*)d_in[0];
    const float* Win = (const float*)d_in[1];
    const float* Wh  = (const float*)d_in[2];
    const float* bh  = (const float*)d_in[3];
    float* out = (float*)d_out;
    char* ws = (char*)d_ws;
    f16* Xp       = (f16*)(ws + XP_OFF);
    f16* Wf       = (f16*)(ws + WF_OFF);
    uint32_t* Whp = (uint32_t*)(ws + WHP_OFF);
    uint32_t* Wst = (uint32_t*)(ws + WST_OFF);

    prep_kernel<<<1024, 256, 0, stream>>>(Win, Wh, Wf, Whp, Wst);
    gemm_kernel<<<dim3(4, 512), 256, 0, stream>>>(X, Wf, bh, Xp);
    rnn_kernel<<<BATCH, 512, 0, stream>>>(Whp, Wst, Xp, out);
}